// Round 9
// baseline (217.888 us; speedup 1.0000x reference)
//
#include <hip/hip_runtime.h>
#include <hip/hip_bf16.h>

#define N_NODES 50000
#define N_EDGES 800000
#define C 128

#define NBB   391      // buckets of 128 nodes: bucket = dst >> 7
#define CAPB  2600     // per-bucket capacity (mean 2046, +12 sigma)
#define CHUNK 2048     // edges per binA block

typedef __attribute__((ext_vector_type(8))) short short8v;  // 8 bf16 (4 VGPR)
typedef __attribute__((ext_vector_type(4))) float f32x4;    // MFMA C/D

// ---------------------------------------------------------------------------
// bf16 pack helpers (RTN)
// ---------------------------------------------------------------------------
__device__ __forceinline__ unsigned int bf16rtn(float f) {
    unsigned int u = __float_as_uint(f);
    return (u + 0x7fffu + ((u >> 16) & 1u)) >> 16;
}
__device__ __forceinline__ unsigned int packbf2(float lo, float hi) {
    return bf16rtn(lo) | (bf16rtn(hi) << 16);
}

// ---------------------------------------------------------------------------
// k_prepW: split W (f32 [k][col]) into Wh + Wl bf16 stored [col][k] (B^T rows
// = MFMA B-frag layout). Also zeroes gcur (absorbs the old memset dispatch).
// ---------------------------------------------------------------------------
__global__ void k_prepW(const float* __restrict__ W1, const float* __restrict__ W2,
                        unsigned short* __restrict__ Wsplit, int* __restrict__ gcur) {
    int t = blockIdx.x * 256 + threadIdx.x;   // 0..32767
    if (t < NBB) gcur[t] = 0;
    if (t >= 32768) return;
    int layer = t >> 14, idx = t & 16383;
    int i = idx >> 7, j = idx & 127;          // i = k (in), j = col (out)
    const float* Wsrc = layer ? W2 : W1;
    float w = Wsrc[i * 128 + j];
    unsigned int h = bf16rtn(w);
    float hf = __uint_as_float(h << 16);
    unsigned int l = bf16rtn(w - hf);
    unsigned short* base = Wsplit + layer * 32768;
    base[j * 128 + i] = (unsigned short)h;
    base[16384 + j * 128 + i] = (unsigned short)l;
}

// ---------------------------------------------------------------------------
// k_binA: single-level radix partition; shfl-based scan (2 barriers).
// ---------------------------------------------------------------------------
__global__ __launch_bounds__(256) void k_binA(const int* __restrict__ ei,
                                              int* __restrict__ gcur,
                                              int2* __restrict__ tmp) {
    __shared__ int hist[NBB];
    __shared__ int lbase[NBB];
    __shared__ int gbaseL[NBB];
    __shared__ int wsum[4];
    __shared__ int2 buf[CHUNK];
    __shared__ int totalv;

    int tid = threadIdx.x;
    int e0 = blockIdx.x * CHUNK;

    for (int i = tid; i < NBB; i += 256) hist[i] = 0;
    __syncthreads();

    int sarr[8], darr[8], parr[8];
#pragma unroll
    for (int j = 0; j < 8; ++j) {
        int e = e0 + j * 256 + tid;
        darr[j] = -1;
        if (e < N_EDGES) {
            sarr[j] = ei[e];
            int d = ei[N_EDGES + e];
            darr[j] = d;
            parr[j] = atomicAdd(&hist[d >> 7], 1);
        }
    }
    __syncthreads();

    {   // exclusive scan of hist (thread t owns buckets 2t,2t+1); shfl scan
        int i0 = 2 * tid, i1 = i0 + 1;
        int c0 = (i0 < NBB) ? hist[i0] : 0;
        int c1 = (i1 < NBB) ? hist[i1] : 0;
        int c = c0 + c1;
        int lane = tid & 63, w = tid >> 6;
        int s = c;
#pragma unroll
        for (int d = 1; d < 64; d <<= 1) {
            int u = __shfl_up(s, d, 64);
            if (lane >= d) s += u;
        }
        if (lane == 63) wsum[w] = s;
        __syncthreads();
        int add = 0;
        for (int i = 0; i < w; ++i) add += wsum[i];
        int incl = s + add;
        int excl = incl - c;
        if (i0 < NBB) lbase[i0] = excl;
        if (i1 < NBB) lbase[i1] = excl + c0;
        if (tid == 255) totalv = incl;
    }
    // reserve global runs (one atomic per non-empty bucket per block)
    for (int i = tid; i < NBB; i += 256) {
        int cnt = hist[i];
        int run = (cnt > 0) ? atomicAdd(&gcur[i], cnt) : 0;
        gbaseL[i] = i * CAPB + run;
    }
    __syncthreads();

#pragma unroll
    for (int j = 0; j < 8; ++j) {
        if (darr[j] >= 0) {
            int b = darr[j] >> 7;
            buf[lbase[b] + parr[j]] = make_int2(sarr[j], darr[j]);
        }
    }
    __syncthreads();

    int total = totalv;
    for (int i = tid; i < total; i += 256) {
        int2 v = buf[i];
        int b = v.y >> 7;
        int gpos = gbaseL[b] + (i - lbase[b]);
        if (gpos < (b + 1) * CAPB) tmp[gpos] = v;
    }
}

// ---------------------------------------------------------------------------
// k_dinv: per-node in-degree, dinv = rsqrt(deg+1)  (consumed by k_gemm).
// ---------------------------------------------------------------------------
__global__ __launch_bounds__(256) void k_dinv(const int2* __restrict__ tmp,
                                              const int* __restrict__ gcur,
                                              float* __restrict__ dinv) {
    __shared__ int cnt[128];
    int b = blockIdx.x, tid = threadIdx.x;
    if (tid < 128) cnt[tid] = 0;
    __syncthreads();
    int n = gcur[b];
    if (n > CAPB) n = CAPB;
    for (int i = tid; i < n; i += 256)
        atomicAdd(&cnt[tmp[b * CAPB + i].y & 127], 1);
    __syncthreads();
    int node = b * 128 + tid;
    if (tid < 128 && node < N_NODES)
        dinv[node] = rsqrtf((float)cnt[tid] + 1.0f);
}

// ---------------------------------------------------------------------------
// MFMA GEMM (2-term W-split): Hout[r][c] = bf16( dinv[r] * (A[r] @ (Wh+Wl)) )
// AF32=true: A is f32 (layer 1). AF32=false: A is bf16 rows, relu pre-applied
// by agg1 (bit-identical to relu-in-gemm since bf16rtn∘relu ≡ relu∘bf16rtn).
// ---------------------------------------------------------------------------
template <bool AF32>
__global__ __launch_bounds__(512, 4) void k_gemm(const void* __restrict__ Ain,
                                                 const unsigned short* __restrict__ Whg,
                                                 const unsigned short* __restrict__ Wlg,
                                                 const float* __restrict__ dinv,
                                                 unsigned short* __restrict__ Hout) {
    __shared__ uint4 Al[64 * 16];   // [64 rows][128 k] bf16, XOR-swizzled
    __shared__ float ddv[64];

    int tid = threadIdx.x;
    int row0 = blockIdx.x * 64;
    int wv = tid >> 6, lane = tid & 63;
    int col = wv * 16 + (lane & 15);
    int kq = lane >> 4;               // k-quarter

    const uint4* Bh4 = (const uint4*)Whg;
    const uint4* Bl4 = (const uint4*)Wlg;
    short8v bh[4], bl[4];
#pragma unroll
    for (int ks = 0; ks < 4; ++ks) {
        uint4 uh = Bh4[col * 16 + ks * 4 + kq];
        uint4 ul = Bl4[col * 16 + ks * 4 + kq];
        bh[ks] = *reinterpret_cast<short8v*>(&uh);
        bl[ks] = *reinterpret_cast<short8v*>(&ul);
    }

    // Stage A tile (64 rows x 128 k) as bf16, swizzled. 2 passes x 512 thr.
#pragma unroll
    for (int pass = 0; pass < 2; ++pass) {
        int row = (tid >> 4) + pass * 32;
        int o = tid & 15;             // k-octet
        int gr = row0 + row;
        uint4 u = make_uint4(0u, 0u, 0u, 0u);
        if (AF32) {
            float4 v0 = make_float4(0.f, 0.f, 0.f, 0.f), v1 = v0;
            if (gr < N_NODES) {
                const float4* A4 = (const float4*)Ain;
                v0 = A4[gr * 32 + o * 2];
                v1 = A4[gr * 32 + o * 2 + 1];
            }
            u.x = packbf2(v0.x, v0.y);
            u.y = packbf2(v0.z, v0.w);
            u.z = packbf2(v1.x, v1.y);
            u.w = packbf2(v1.z, v1.w);
        } else {
            if (gr < N_NODES) u = ((const uint4*)Ain)[gr * 16 + o];
        }
        int byte = (row * 256 + o * 16) ^ ((row & 7) << 4);
        Al[byte >> 4] = u;
    }
    if (tid < 64) {
        int gr = row0 + tid;
        ddv[tid] = (gr < N_NODES) ? dinv[gr] : 0.f;
    }
    __syncthreads();

    f32x4 acc[4];
#pragma unroll
    for (int st = 0; st < 4; ++st) acc[st] = (f32x4){0.f, 0.f, 0.f, 0.f};

#pragma unroll
    for (int st = 0; st < 4; ++st) {
        int rowl = st * 16 + (lane & 15);
        int rbase = rowl * 256;
        int swz = (rowl & 7) << 4;
#pragma unroll
        for (int ks = 0; ks < 4; ++ks) {
            int byte = (rbase + ks * 64 + kq * 16) ^ swz;
            uint4 ua = Al[byte >> 4];
            short8v a = *reinterpret_cast<short8v*>(&ua);
            acc[st] = __builtin_amdgcn_mfma_f32_16x16x32_bf16(a, bh[ks], acc[st], 0, 0, 0);
            acc[st] = __builtin_amdgcn_mfma_f32_16x16x32_bf16(a, bl[ks], acc[st], 0, 0, 0);
        }
    }

    // Epilogue: D lane l reg r -> row (l>>4)*4+r within stripe, col.
#pragma unroll
    for (int st = 0; st < 4; ++st) {
#pragma unroll
        for (int r = 0; r < 4; ++r) {
            int rowl = st * 16 + kq * 4 + r;
            int gr = row0 + rowl;
            if (gr < N_NODES) {
                float dv = ddv[rowl];
                Hout[gr * 128 + col] = (unsigned short)bf16rtn(dv * acc[st][r]);
            }
        }
    }
}

// ---------------------------------------------------------------------------
// Fused half-bucket aggregation: 512 thr (8 waves) per 64-node half-bucket,
// 782 blocks (all resident in one round). Stage bucket edges, build local
// CSR for this half's 64 nodes (single-wave shfl scan), then each wave
// aggregates 8 nodes with a 16-edge/iter gather (4 row loads in flight per
// lane). h pre-scaled by dinv[src] so gather is a pure row-sum.
// FINAL=false: write relu'd bf16 rows (feeds gemm2). FINAL=true: fused
// relu + 128->1 linear -> out.
// ---------------------------------------------------------------------------
__device__ __forceinline__ void add8(float* acc, uint4 u) {
    acc[0] += __uint_as_float(u.x << 16);
    acc[1] += __uint_as_float(u.x & 0xffff0000u);
    acc[2] += __uint_as_float(u.y << 16);
    acc[3] += __uint_as_float(u.y & 0xffff0000u);
    acc[4] += __uint_as_float(u.z << 16);
    acc[5] += __uint_as_float(u.z & 0xffff0000u);
    acc[6] += __uint_as_float(u.w << 16);
    acc[7] += __uint_as_float(u.w & 0xffff0000u);
}

template <bool FINAL>
__global__ __launch_bounds__(512, 6) void k_agg(const uint4* __restrict__ h4,
                                                const int2* __restrict__ tmp,
                                                const int* __restrict__ gcur,
                                                const float* __restrict__ bias,
                                                const float* __restrict__ Wlin,
                                                const float* __restrict__ blin,
                                                void* __restrict__ aggout) {
    __shared__ int   rawsrc[CAPB];
    __shared__ short rawloc[CAPB];
    __shared__ int   lcsr[CAPB];
    __shared__ int   lcnt[64];
    __shared__ int   lbase0[64];
    __shared__ int   lcur[64];

    int blk = blockIdx.x;
    int b = blk >> 1, half = blk & 1;
    int tid = threadIdx.x;
    int cnt = gcur[b];
    if (cnt > CAPB) cnt = CAPB;

    if (tid < 64) { lcnt[tid] = 0; lcur[tid] = 0; }
    __syncthreads();

    const int2* tmpb = tmp + (size_t)b * CAPB;
    for (int i = tid; i < cnt; i += 512) {
        int2 v = tmpb[i];
        int l = v.y & 127;
        rawsrc[i] = v.x;
        rawloc[i] = (short)l;
        if ((l >> 6) == half) atomicAdd(&lcnt[l & 63], 1);
    }
    __syncthreads();

    if (tid < 64) {   // single-wave shfl exclusive scan over 64 node counts
        int c = lcnt[tid];
        int s = c;
#pragma unroll
        for (int d = 1; d < 64; d <<= 1) {
            int u = __shfl_up(s, d, 64);
            if (tid >= d) s += u;
        }
        lbase0[tid] = s - c;
    }
    __syncthreads();

    for (int i = tid; i < cnt; i += 512) {
        int l = rawloc[i];
        if ((l >> 6) == half) {
            int ll = l & 63;
            int p = atomicAdd(&lcur[ll], 1);
            lcsr[lbase0[ll] + p] = rawsrc[i];
        }
    }
    __syncthreads();

    int wv = tid >> 6, lane = tid & 63, eg = lane >> 4, cq = lane & 15;

    float4 bv0 = ((const float4*)bias)[cq * 2];
    float4 bv1 = ((const float4*)bias)[cq * 2 + 1];
    float4 wl0 = make_float4(0.f, 0.f, 0.f, 0.f), wl1 = wl0;
    float bl = 0.f;
    if (FINAL) {
        wl0 = ((const float4*)Wlin)[cq * 2];
        wl1 = ((const float4*)Wlin)[cq * 2 + 1];
        bl = blin[0];
    }

#pragma unroll 1
    for (int t = 0; t < 8; ++t) {
        int ll = wv * 8 + t;
        int node = b * 128 + half * 64 + ll;
        if (node >= N_NODES) break;   // uniform per wave (monotone)
        int deg = lcnt[ll];
        int o0 = lbase0[ll], o1 = o0 + deg;

        uint4 us = h4[node * 16 + cq];   // self-term row: issue early

        float acc[8];
#pragma unroll
        for (int j = 0; j < 8; ++j) acc[j] = 0.f;

        int e = o0;
        // 16 edges/iter: 4 independent row loads in flight per lane
        for (; e + 16 <= o1; e += 16) {
            int b0 = e + 4 * eg;
            int s0 = lcsr[b0], s1 = lcsr[b0 + 1], s2 = lcsr[b0 + 2], s3 = lcsr[b0 + 3];
            uint4 u0 = h4[s0 * 16 + cq];
            uint4 u1 = h4[s1 * 16 + cq];
            uint4 u2 = h4[s2 * 16 + cq];
            uint4 u3 = h4[s3 * 16 + cq];
            add8(acc, u0); add8(acc, u1); add8(acc, u2); add8(acc, u3);
        }
        if (e + 8 <= o1) {
            int b0 = e + 2 * eg;
            int s0 = lcsr[b0], s1 = lcsr[b0 + 1];
            uint4 u0 = h4[s0 * 16 + cq];
            uint4 u1 = h4[s1 * 16 + cq];
            add8(acc, u0); add8(acc, u1);
            e += 8;
        }
        {   // tail < 8
            int r = o1 - e;
            int b0 = e + 2 * eg;
            if (2 * eg < r)     add8(acc, h4[lcsr[b0] * 16 + cq]);
            if (2 * eg + 1 < r) add8(acc, h4[lcsr[b0 + 1] * 16 + cq]);
        }
#pragma unroll
        for (int j = 0; j < 8; ++j) {
            acc[j] += __shfl_xor(acc[j], 16, 64);
            acc[j] += __shfl_xor(acc[j], 32, 64);
        }

        float dv = rsqrtf((float)deg + 1.0f);
        float hv[8];
        hv[0] = __uint_as_float(us.x << 16); hv[1] = __uint_as_float(us.x & 0xffff0000u);
        hv[2] = __uint_as_float(us.y << 16); hv[3] = __uint_as_float(us.y & 0xffff0000u);
        hv[4] = __uint_as_float(us.z << 16); hv[5] = __uint_as_float(us.z & 0xffff0000u);
        hv[6] = __uint_as_float(us.w << 16); hv[7] = __uint_as_float(us.w & 0xffff0000u);
        float o[8];
        o[0] = dv * (acc[0] + hv[0]) + bv0.x;
        o[1] = dv * (acc[1] + hv[1]) + bv0.y;
        o[2] = dv * (acc[2] + hv[2]) + bv0.z;
        o[3] = dv * (acc[3] + hv[3]) + bv0.w;
        o[4] = dv * (acc[4] + hv[4]) + bv1.x;
        o[5] = dv * (acc[5] + hv[5]) + bv1.y;
        o[6] = dv * (acc[6] + hv[6]) + bv1.z;
        o[7] = dv * (acc[7] + hv[7]) + bv1.w;

        if (!FINAL) {
            if (eg == 0) {   // relu + bf16 pack (bit-identical to relu-in-gemm)
                uint4 u;
                u.x = packbf2(fmaxf(o[0], 0.f), fmaxf(o[1], 0.f));
                u.y = packbf2(fmaxf(o[2], 0.f), fmaxf(o[3], 0.f));
                u.z = packbf2(fmaxf(o[4], 0.f), fmaxf(o[5], 0.f));
                u.w = packbf2(fmaxf(o[6], 0.f), fmaxf(o[7], 0.f));
                ((uint4*)aggout)[node * 16 + cq] = u;
            }
        } else {
            float v = fmaxf(o[0], 0.f) * wl0.x + fmaxf(o[1], 0.f) * wl0.y
                    + fmaxf(o[2], 0.f) * wl0.z + fmaxf(o[3], 0.f) * wl0.w
                    + fmaxf(o[4], 0.f) * wl1.x + fmaxf(o[5], 0.f) * wl1.y
                    + fmaxf(o[6], 0.f) * wl1.z + fmaxf(o[7], 0.f) * wl1.w;
            v += __shfl_xor(v, 1, 64);
            v += __shfl_xor(v, 2, 64);
            v += __shfl_xor(v, 4, 64);
            v += __shfl_xor(v, 8, 64);
            if (lane == 0) ((float*)aggout)[node] = v + bl;
        }
    }
}

// ---------------------------------------------------------------------------
extern "C" void kernel_launch(void* const* d_in, const int* in_sizes, int n_in,
                              void* d_out, int out_size, void* d_ws, size_t ws_size,
                              hipStream_t stream) {
    const float* x    = (const float*)d_in[0];
    const int*   ei   = (const int*)d_in[2];
    const float* W1   = (const float*)d_in[4];
    const float* b1   = (const float*)d_in[5];
    const float* W2   = (const float*)d_in[6];
    const float* b2   = (const float*)d_in[7];
    const float* Wlin = (const float*)d_in[8];
    const float* blin = (const float*)d_in[9];
    float* out = (float*)d_out;

    char* ws = (char*)d_ws;
    size_t off = 0;
    auto carve = [&](size_t bytes) -> void* {
        void* p = ws + off;
        off = (off + bytes + 255) & ~(size_t)255;
        return p;
    };
    int*   gcur = (int*)  carve(NBB * sizeof(int));
    float* dinv = (float*)carve(N_NODES * sizeof(float));
    int2*  tmp  = (int2*) carve((size_t)NBB * CAPB * sizeof(int2));   // 8.1 MB
    unsigned short* hbf  = (unsigned short*)carve((size_t)N_NODES * C * sizeof(unsigned short));
    unsigned short* hbf2 = (unsigned short*)carve((size_t)N_NODES * C * sizeof(unsigned short));
    unsigned short* wsplit = (unsigned short*)carve(4 * 16384 * sizeof(unsigned short));

    const int NB_A = (N_EDGES + CHUNK - 1) / CHUNK;   // 391
    const int NB_G = (N_NODES + 63) / 64;             // 782
    const int NB_H = 2 * NBB;                          // 782 half-bucket blocks

    const unsigned short* W1h = wsplit;
    const unsigned short* W1l = wsplit + 16384;
    const unsigned short* W2h = wsplit + 32768;
    const unsigned short* W2l = wsplit + 49152;

    // prep (also zeroes gcur) + edge partition + degrees
    k_prepW<<<128, 256, 0, stream>>>(W1, W2, wsplit, gcur);
    k_binA<<<NB_A, 256, 0, stream>>>(ei, gcur, tmp);
    k_dinv<<<NBB, 256, 0, stream>>>(tmp, gcur, dinv);

    // Layer 1: h1 = bf16(dinv * (x @ W1));  agg1 -> relu'd bf16 rows
    k_gemm<true><<<NB_G, 512, 0, stream>>>(x, W1h, W1l, dinv, hbf);
    k_agg<false><<<NB_H, 512, 0, stream>>>((const uint4*)hbf, tmp, gcur,
                                           b1, Wlin, blin, hbf2);
    // Layer 2: h2 = bf16(dinv * (relu(agg1) @ W2));  agg2 + final linear
    k_gemm<false><<<NB_G, 512, 0, stream>>>(hbf2, W2h, W2l, dinv, hbf);
    k_agg<true><<<NB_H, 512, 0, stream>>>((const uint4*)hbf, tmp, gcur,
                                          b2, Wlin, blin, out);
}

// Round 10
// 202.767 us; speedup vs baseline: 1.0746x; 1.0746x over previous
//
#include <hip/hip_runtime.h>
#include <hip/hip_bf16.h>

#define N_NODES 50000
#define N_EDGES 800000
#define C 128

#define NBB   391      // buckets of 128 nodes: bucket = dst >> 7
#define CAPB  3072     // tmp per-bucket capacity (mean 2046, +22 sigma)
#define CAPC  3456     // csr per-bucket capacity (CAPB + 128*3 pad)
#define CHUNK 2048     // edges per binA block

typedef __attribute__((ext_vector_type(8))) short short8v;  // 8 bf16 (4 VGPR)
typedef __attribute__((ext_vector_type(4))) float f32x4;    // MFMA C/D

// ---------------------------------------------------------------------------
// bf16 pack helpers (RTN)
// ---------------------------------------------------------------------------
__device__ __forceinline__ unsigned int bf16rtn(float f) {
    unsigned int u = __float_as_uint(f);
    return (u + 0x7fffu + ((u >> 16) & 1u)) >> 16;
}
__device__ __forceinline__ unsigned int packbf2(float lo, float hi) {
    return bf16rtn(lo) | (bf16rtn(hi) << 16);
}

// ---------------------------------------------------------------------------
// k_prepW: split W (f32 [k][col]) into Wh + Wl bf16 stored [col][k] (B^T rows
// = MFMA B-frag layout). Also zeroes gcur (absorbs the memset dispatch).
// ---------------------------------------------------------------------------
__global__ void k_prepW(const float* __restrict__ W1, const float* __restrict__ W2,
                        unsigned short* __restrict__ Wsplit, int* __restrict__ gcur) {
    int t = blockIdx.x * 256 + threadIdx.x;   // 0..32767
    if (t < NBB) gcur[t] = 0;
    if (t >= 32768) return;
    int layer = t >> 14, idx = t & 16383;
    int i = idx >> 7, j = idx & 127;          // i = k (in), j = col (out)
    const float* Wsrc = layer ? W2 : W1;
    float w = Wsrc[i * 128 + j];
    unsigned int h = bf16rtn(w);
    float hf = __uint_as_float(h << 16);
    unsigned int l = bf16rtn(w - hf);
    unsigned short* base = Wsplit + layer * 32768;
    base[j * 128 + i] = (unsigned short)h;
    base[16384 + j * 128 + i] = (unsigned short)l;
}

// ---------------------------------------------------------------------------
// k_binA: single-level radix partition (shfl scan). Blocks of CHUNK edges;
// LDS histogram by bucket (dst>>7), local scatter, one global atomic per
// bucket per block, coalesced run write into tmp's bucket-strided windows.
// ---------------------------------------------------------------------------
__global__ __launch_bounds__(256) void k_binA(const int* __restrict__ ei,
                                              int* __restrict__ gcur,
                                              int2* __restrict__ tmp) {
    __shared__ int hist[NBB];
    __shared__ int lbase[NBB];
    __shared__ int gbaseL[NBB];
    __shared__ int wsum[4];
    __shared__ int2 buf[CHUNK];
    __shared__ int totalv;

    int tid = threadIdx.x;
    int e0 = blockIdx.x * CHUNK;

    for (int i = tid; i < NBB; i += 256) hist[i] = 0;
    __syncthreads();

    int sarr[8], darr[8], parr[8];
#pragma unroll
    for (int j = 0; j < 8; ++j) {
        int e = e0 + j * 256 + tid;
        darr[j] = -1;
        if (e < N_EDGES) {
            sarr[j] = ei[e];
            int d = ei[N_EDGES + e];
            darr[j] = d;
            parr[j] = atomicAdd(&hist[d >> 7], 1);
        }
    }
    __syncthreads();

    {   // exclusive scan of hist (thread t owns buckets 2t,2t+1); shfl scan
        int i0 = 2 * tid, i1 = i0 + 1;
        int c0 = (i0 < NBB) ? hist[i0] : 0;
        int c1 = (i1 < NBB) ? hist[i1] : 0;
        int c = c0 + c1;
        int lane = tid & 63, w = tid >> 6;
        int s = c;
#pragma unroll
        for (int d = 1; d < 64; d <<= 1) {
            int u = __shfl_up(s, d, 64);
            if (lane >= d) s += u;
        }
        if (lane == 63) wsum[w] = s;
        __syncthreads();
        int add = 0;
        for (int i = 0; i < w; ++i) add += wsum[i];
        int incl = s + add;
        int excl = incl - c;
        if (i0 < NBB) lbase[i0] = excl;
        if (i1 < NBB) lbase[i1] = excl + c0;
        if (tid == 255) totalv = incl;
    }
    for (int i = tid; i < NBB; i += 256) {
        int cnt = hist[i];
        int run = (cnt > 0) ? atomicAdd(&gcur[i], cnt) : 0;
        gbaseL[i] = i * CAPB + run;
    }
    __syncthreads();

#pragma unroll
    for (int j = 0; j < 8; ++j) {
        if (darr[j] >= 0) {
            int b = darr[j] >> 7;
            buf[lbase[b] + parr[j]] = make_int2(sarr[j], darr[j]);
        }
    }
    __syncthreads();

    int total = totalv;
    for (int i = tid; i < total; i += 256) {
        int2 v = buf[i];
        int b = v.y >> 7;
        int gpos = gbaseL[b] + (i - lbase[b]);
        if (gpos < (b + 1) * CAPB) tmp[gpos] = v;
    }
}

// ---------------------------------------------------------------------------
// k_csr: one block per bucket. Sorts the bucket's edges into per-node
// contiguous lists in csr (bucket-strided, node-list starts 4-int aligned),
// writes offn/degn/dinv. Runs ONCE; both agg passes reuse the result.
// ---------------------------------------------------------------------------
__global__ __launch_bounds__(256) void k_csr(const int2* __restrict__ tmp,
                                             const int* __restrict__ gcur,
                                             int* __restrict__ csr,
                                             int* __restrict__ offn,
                                             int* __restrict__ degn,
                                             float* __restrict__ dinv) {
    __shared__ int   rawsrc[CAPB];
    __shared__ short rawloc[CAPB];
    __shared__ int   lcnt[128];
    __shared__ int   lbase[128];
    __shared__ int   lcur[128];

    int b = blockIdx.x, tid = threadIdx.x;
    int cnt = gcur[b];
    if (cnt > CAPB) cnt = CAPB;

    if (tid < 128) { lcnt[tid] = 0; lcur[tid] = 0; }
    __syncthreads();

    const int2* tmpb = tmp + (size_t)b * CAPB;
    for (int i = tid; i < cnt; i += 256) {
        int2 v = tmpb[i];
        int l = v.y & 127;
        rawsrc[i] = v.x;
        rawloc[i] = (short)l;
        atomicAdd(&lcnt[l], 1);
    }
    __syncthreads();

    if (tid < 64) {   // scan of 4-padded counts (keeps each list 16B-aligned)
        int c0 = lcnt[2 * tid], c1 = lcnt[2 * tid + 1];
        int p0 = (c0 + 3) & ~3, p1 = (c1 + 3) & ~3;
        int c = p0 + p1;
        int s = c;
#pragma unroll
        for (int d = 1; d < 64; d <<= 1) {
            int u = __shfl_up(s, d, 64);
            if (tid >= d) s += u;
        }
        int excl = s - c;
        lbase[2 * tid] = excl;
        lbase[2 * tid + 1] = excl + p0;
    }
    __syncthreads();

    int node = b * 128 + tid;
    if (tid < 128 && node < N_NODES) {
        offn[node] = b * CAPC + lbase[tid];
        degn[node] = lcnt[tid];
        dinv[node] = rsqrtf((float)lcnt[tid] + 1.0f);
    }

    for (int i = tid; i < cnt; i += 256) {
        int l = rawloc[i];
        int p = atomicAdd(&lcur[l], 1);
        csr[b * CAPC + lbase[l] + p] = rawsrc[i];
    }
}

// ---------------------------------------------------------------------------
// MFMA GEMM (2-term W-split): Hout[r][c] = bf16( dinv[r] * (A[r] @ (Wh+Wl)) )
// AF32=true: A f32 (layer 1). AF32=false: A bf16 rows (relu pre-applied).
// ---------------------------------------------------------------------------
template <bool AF32>
__global__ __launch_bounds__(512, 4) void k_gemm(const void* __restrict__ Ain,
                                                 const unsigned short* __restrict__ Whg,
                                                 const unsigned short* __restrict__ Wlg,
                                                 const float* __restrict__ dinv,
                                                 unsigned short* __restrict__ Hout) {
    __shared__ uint4 Al[64 * 16];   // [64 rows][128 k] bf16, XOR-swizzled
    __shared__ float ddv[64];

    int tid = threadIdx.x;
    int row0 = blockIdx.x * 64;
    int wv = tid >> 6, lane = tid & 63;
    int col = wv * 16 + (lane & 15);
    int kq = lane >> 4;

    const uint4* Bh4 = (const uint4*)Whg;
    const uint4* Bl4 = (const uint4*)Wlg;
    short8v bh[4], bl[4];
#pragma unroll
    for (int ks = 0; ks < 4; ++ks) {
        uint4 uh = Bh4[col * 16 + ks * 4 + kq];
        uint4 ul = Bl4[col * 16 + ks * 4 + kq];
        bh[ks] = *reinterpret_cast<short8v*>(&uh);
        bl[ks] = *reinterpret_cast<short8v*>(&ul);
    }

#pragma unroll
    for (int pass = 0; pass < 2; ++pass) {
        int row = (tid >> 4) + pass * 32;
        int o = tid & 15;
        int gr = row0 + row;
        uint4 u = make_uint4(0u, 0u, 0u, 0u);
        if (AF32) {
            float4 v0 = make_float4(0.f, 0.f, 0.f, 0.f), v1 = v0;
            if (gr < N_NODES) {
                const float4* A4 = (const float4*)Ain;
                v0 = A4[gr * 32 + o * 2];
                v1 = A4[gr * 32 + o * 2 + 1];
            }
            u.x = packbf2(v0.x, v0.y);
            u.y = packbf2(v0.z, v0.w);
            u.z = packbf2(v1.x, v1.y);
            u.w = packbf2(v1.z, v1.w);
        } else {
            if (gr < N_NODES) u = ((const uint4*)Ain)[gr * 16 + o];
        }
        int byte = (row * 256 + o * 16) ^ ((row & 7) << 4);
        Al[byte >> 4] = u;
    }
    if (tid < 64) {
        int gr = row0 + tid;
        ddv[tid] = (gr < N_NODES) ? dinv[gr] : 0.f;
    }
    __syncthreads();

    f32x4 acc[4];
#pragma unroll
    for (int st = 0; st < 4; ++st) acc[st] = (f32x4){0.f, 0.f, 0.f, 0.f};

#pragma unroll
    for (int st = 0; st < 4; ++st) {
        int rowl = st * 16 + (lane & 15);
        int rbase = rowl * 256;
        int swz = (rowl & 7) << 4;
#pragma unroll
        for (int ks = 0; ks < 4; ++ks) {
            int byte = (rbase + ks * 64 + kq * 16) ^ swz;
            uint4 ua = Al[byte >> 4];
            short8v a = *reinterpret_cast<short8v*>(&ua);
            acc[st] = __builtin_amdgcn_mfma_f32_16x16x32_bf16(a, bh[ks], acc[st], 0, 0, 0);
            acc[st] = __builtin_amdgcn_mfma_f32_16x16x32_bf16(a, bl[ks], acc[st], 0, 0, 0);
        }
    }

#pragma unroll
    for (int st = 0; st < 4; ++st) {
#pragma unroll
        for (int r = 0; r < 4; ++r) {
            int rowl = st * 16 + kq * 4 + r;
            int gr = row0 + rowl;
            if (gr < N_NODES) {
                float dv = ddv[rowl];
                Hout[gr * 128 + col] = (unsigned short)bf16rtn(dv * acc[st][r]);
            }
        }
    }
}

// ---------------------------------------------------------------------------
// Wave-per-node aggregation on the global CSR. 12500 blocks x 256 thr, no
// LDS. Lane split: eg=lane>>4 (edge group), cq=lane&15 (channel quad).
// 16 edges in flight per wave (int4 index load + 4 row gathers per group).
// h pre-scaled by dinv[src] -> pure row-sum; self-term + dv mul + bias at
// the end. FINAL=false: relu'd bf16 rows out. FINAL=true: relu + 128->1
// linear + wave reduce -> out.
// ---------------------------------------------------------------------------
__device__ __forceinline__ void add8(float* acc, uint4 u) {
    acc[0] += __uint_as_float(u.x << 16);
    acc[1] += __uint_as_float(u.x & 0xffff0000u);
    acc[2] += __uint_as_float(u.y << 16);
    acc[3] += __uint_as_float(u.y & 0xffff0000u);
    acc[4] += __uint_as_float(u.z << 16);
    acc[5] += __uint_as_float(u.z & 0xffff0000u);
    acc[6] += __uint_as_float(u.w << 16);
    acc[7] += __uint_as_float(u.w & 0xffff0000u);
}

template <bool FINAL>
__global__ __launch_bounds__(256) void k_agg(const uint4* __restrict__ h4,
                                             const int* __restrict__ csr,
                                             const int* __restrict__ offn,
                                             const int* __restrict__ degn,
                                             const float* __restrict__ bias,
                                             const float* __restrict__ Wlin,
                                             const float* __restrict__ blin,
                                             void* __restrict__ aggout) {
    int n = (blockIdx.x * 256 + threadIdx.x) >> 6;   // grid sized exactly
    int lane = threadIdx.x & 63, eg = lane >> 4, cq = lane & 15;

    int o0 = offn[n];
    int deg = degn[n];
    int end = o0 + deg;

    uint4 us = h4[n * 16 + cq];   // self-term row: issue early

    float acc[8];
#pragma unroll
    for (int j = 0; j < 8; ++j) acc[j] = 0.f;

    int e = o0;
    for (; e + 16 <= end; e += 16) {
        int4 s4 = *(const int4*)(csr + e + 4 * eg);   // 16B-aligned (padded lists)
        uint4 u0 = h4[s4.x * 16 + cq];
        uint4 u1 = h4[s4.y * 16 + cq];
        uint4 u2 = h4[s4.z * 16 + cq];
        uint4 u3 = h4[s4.w * 16 + cq];
        add8(acc, u0); add8(acc, u1); add8(acc, u2); add8(acc, u3);
    }
    if (e + 8 <= end) {
        int2 s2 = *(const int2*)(csr + e + 2 * eg);   // 8B-aligned
        uint4 u0 = h4[s2.x * 16 + cq];
        uint4 u1 = h4[s2.y * 16 + cq];
        add8(acc, u0); add8(acc, u1);
        e += 8;
    }
    {   // tail < 8
        int r = end - e;
        int b0 = e + 2 * eg;
        if (2 * eg < r)     add8(acc, h4[csr[b0] * 16 + cq]);
        if (2 * eg + 1 < r) add8(acc, h4[csr[b0 + 1] * 16 + cq]);
    }
#pragma unroll
    for (int j = 0; j < 8; ++j) {
        acc[j] += __shfl_xor(acc[j], 16, 64);
        acc[j] += __shfl_xor(acc[j], 32, 64);
    }

    float dv = rsqrtf((float)deg + 1.0f);
    float4 bv0 = ((const float4*)bias)[cq * 2];
    float4 bv1 = ((const float4*)bias)[cq * 2 + 1];
    float hv[8];
    hv[0] = __uint_as_float(us.x << 16); hv[1] = __uint_as_float(us.x & 0xffff0000u);
    hv[2] = __uint_as_float(us.y << 16); hv[3] = __uint_as_float(us.y & 0xffff0000u);
    hv[4] = __uint_as_float(us.z << 16); hv[5] = __uint_as_float(us.z & 0xffff0000u);
    hv[6] = __uint_as_float(us.w << 16); hv[7] = __uint_as_float(us.w & 0xffff0000u);
    float o[8];
    o[0] = dv * (acc[0] + hv[0]) + bv0.x;
    o[1] = dv * (acc[1] + hv[1]) + bv0.y;
    o[2] = dv * (acc[2] + hv[2]) + bv0.z;
    o[3] = dv * (acc[3] + hv[3]) + bv0.w;
    o[4] = dv * (acc[4] + hv[4]) + bv1.x;
    o[5] = dv * (acc[5] + hv[5]) + bv1.y;
    o[6] = dv * (acc[6] + hv[6]) + bv1.z;
    o[7] = dv * (acc[7] + hv[7]) + bv1.w;

    if (!FINAL) {
        if (eg == 0) {   // relu + bf16 pack (bit-identical to relu-in-gemm)
            uint4 u;
            u.x = packbf2(fmaxf(o[0], 0.f), fmaxf(o[1], 0.f));
            u.y = packbf2(fmaxf(o[2], 0.f), fmaxf(o[3], 0.f));
            u.z = packbf2(fmaxf(o[4], 0.f), fmaxf(o[5], 0.f));
            u.w = packbf2(fmaxf(o[6], 0.f), fmaxf(o[7], 0.f));
            ((uint4*)aggout)[n * 16 + cq] = u;
        }
    } else {
        float4 wl0 = ((const float4*)Wlin)[cq * 2];
        float4 wl1 = ((const float4*)Wlin)[cq * 2 + 1];
        float v = fmaxf(o[0], 0.f) * wl0.x + fmaxf(o[1], 0.f) * wl0.y
                + fmaxf(o[2], 0.f) * wl0.z + fmaxf(o[3], 0.f) * wl0.w
                + fmaxf(o[4], 0.f) * wl1.x + fmaxf(o[5], 0.f) * wl1.y
                + fmaxf(o[6], 0.f) * wl1.z + fmaxf(o[7], 0.f) * wl1.w;
        v += __shfl_xor(v, 1, 64);
        v += __shfl_xor(v, 2, 64);
        v += __shfl_xor(v, 4, 64);
        v += __shfl_xor(v, 8, 64);
        if (lane == 0) ((float*)aggout)[n] = v + blin[0];
    }
}

// ---------------------------------------------------------------------------
extern "C" void kernel_launch(void* const* d_in, const int* in_sizes, int n_in,
                              void* d_out, int out_size, void* d_ws, size_t ws_size,
                              hipStream_t stream) {
    const float* x    = (const float*)d_in[0];
    const int*   ei   = (const int*)d_in[2];
    const float* W1   = (const float*)d_in[4];
    const float* b1   = (const float*)d_in[5];
    const float* W2   = (const float*)d_in[6];
    const float* b2   = (const float*)d_in[7];
    const float* Wlin = (const float*)d_in[8];
    const float* blin = (const float*)d_in[9];
    float* out = (float*)d_out;

    char* ws = (char*)d_ws;
    size_t off = 0;
    auto carve = [&](size_t bytes) -> void* {
        void* p = ws + off;
        off = (off + bytes + 255) & ~(size_t)255;
        return p;
    };
    int*   gcur = (int*)  carve(NBB * sizeof(int));
    float* dinv = (float*)carve(N_NODES * sizeof(float));
    int*   offn = (int*)  carve(N_NODES * sizeof(int));
    int*   degn = (int*)  carve(N_NODES * sizeof(int));
    int2*  tmp  = (int2*) carve((size_t)NBB * CAPB * sizeof(int2));   // 9.6 MB
    int*   csr  = (int*)  carve((size_t)NBB * CAPC * sizeof(int));    // 5.4 MB
    unsigned short* hbf  = (unsigned short*)carve((size_t)N_NODES * C * sizeof(unsigned short));
    unsigned short* hbf2 = (unsigned short*)carve((size_t)N_NODES * C * sizeof(unsigned short));
    unsigned short* wsplit = (unsigned short*)carve(4 * 16384 * sizeof(unsigned short));

    const int NB_A = (N_EDGES + CHUNK - 1) / CHUNK;   // 391
    const int NB_G = (N_NODES + 63) / 64;             // 782
    const int NB_W = (N_NODES * 64) / 256;            // 12500 (exact)

    const unsigned short* W1h = wsplit;
    const unsigned short* W1l = wsplit + 16384;
    const unsigned short* W2h = wsplit + 32768;
    const unsigned short* W2l = wsplit + 49152;

    // prep (zeroes gcur) -> partition -> CSR (+dinv)
    k_prepW<<<128, 256, 0, stream>>>(W1, W2, wsplit, gcur);
    k_binA<<<NB_A, 256, 0, stream>>>(ei, gcur, tmp);
    k_csr<<<NBB, 256, 0, stream>>>(tmp, gcur, csr, offn, degn, dinv);

    // Layer 1: h1 = bf16(dinv * (x @ W1)); agg1 -> relu'd bf16 rows
    k_gemm<true><<<NB_G, 512, 0, stream>>>(x, W1h, W1l, dinv, hbf);
    k_agg<false><<<NB_W, 256, 0, stream>>>((const uint4*)hbf, csr, offn, degn,
                                           b1, Wlin, blin, hbf2);
    // Layer 2: h2 = bf16(dinv * (relu(agg1) @ W2)); agg2 + final linear
    k_gemm<false><<<NB_G, 512, 0, stream>>>(hbf2, W2h, W2l, dinv, hbf);
    k_agg<true><<<NB_W, 256, 0, stream>>>((const uint4*)hbf, csr, offn, degn,
                                          b2, Wlin, blin, out);
}